// Round 8
// baseline (2087.688 us; speedup 1.0000x reference)
//
#include <hip/hip_runtime.h>

#define TSTEPS 2048
#define NENV   256
#define HID    128
#define EPB    16                 // envs per block (= MFMA M/N)
#define NBLK   (NENV / EPB)       // 16 blocks for the scan
#define NTHREADS 512              // 8 waves; wave w owns h-dims [16w,16w+16)

// packed-x layout: [t][eb][kk(4)][quad(4)][l15(16)][8 bf16]  (4KB per (t,eb))
// scan lane(quad,l15) reads its B-frag at base + kk*512 elems (imm offsets).
#define XP_T_STRIDE (NBLK * 2048)                 // 32768 bf16 elems per t
#define XP_BYTES  ((size_t)TSTEPS * XP_T_STRIDE * 2)   // 134 MB

#define LOG2E 1.4426950408889634f

typedef float          floatx4  __attribute__((ext_vector_type(4)));
typedef __bf16         bf16x8   __attribute__((ext_vector_type(8)));
typedef unsigned short ushortx8 __attribute__((ext_vector_type(8)));
typedef unsigned int   uintx4   __attribute__((ext_vector_type(4)));
typedef unsigned int   uintx2   __attribute__((ext_vector_type(2)));

// fp32 -> bf16 round-to-nearest-even (scalar fallback)
__device__ __forceinline__ unsigned short f2bf(float f) {
    unsigned u = __float_as_uint(f);
    u += 0x7FFFu + ((u >> 16) & 1u);
    return (unsigned short)(u >> 16);
}

// packed fp32x2 -> bf16x2 (gfx950 v_cvt_pk_bf16_f32 when available)
__device__ __forceinline__ unsigned cvt_pk_bf16(float a, float b) {
#if __has_builtin(__builtin_amdgcn_cvt_pk_bf16_f32)
    typedef __bf16 bf16x2 __attribute__((ext_vector_type(2)));
    bf16x2 r = __builtin_amdgcn_cvt_pk_bf16_f32(a, b);
    return __builtin_bit_cast(unsigned, r);
#else
    return (unsigned)f2bf(a) | ((unsigned)f2bf(b) << 16);
#endif
}

__device__ __forceinline__ bf16x8 pack8(floatx4 a, floatx4 b) {
    uintx4 u;
    u[0] = cvt_pk_bf16(a[0], a[1]);
    u[1] = cvt_pk_bf16(a[2], a[3]);
    u[2] = cvt_pk_bf16(b[0], b[1]);
    u[3] = cvt_pk_bf16(b[2], b[3]);
    return __builtin_bit_cast(bf16x8, u);
}

__device__ __forceinline__ float fast_rcp(float x) {
#if __has_builtin(__builtin_amdgcn_rcpf)
    return __builtin_amdgcn_rcpf(x);
#else
    return 1.0f / x;
#endif
}
// raw 2^x (inputs are pre-scaled by +/-log2e at weight-pack time)
__device__ __forceinline__ float exp2_fast(float x) {
#if __has_builtin(__builtin_amdgcn_exp2f)
    return __builtin_amdgcn_exp2f(x);
#else
    float r; asm("v_exp_f32 %0, %1" : "=v"(r) : "v"(x)); return r;
#endif
}
// legacy helpers for the fused fallback kernel
__device__ __forceinline__ float sigm(float x) {
    return fast_rcp(1.0f + __expf(-x));
}
__device__ __forceinline__ float tanh_fast(float x) {
    return 1.0f - 2.0f * fast_rcp(1.0f + __expf(2.0f * x));
}

// ---------------------------------------------------------------------------
// Phase 1: pack x into bf16 MFMA B-fragments, coalesced BOTH sides via a
// swizzled LDS transpose. Grid: 4096 blocks x 256 threads, 8 slabs/block.
// Slab s = t*16+eb: x source is 2048 contiguous floats (8KB), xp dest is
// 2048 contiguous bf16 (4KB). Read: thread tid takes 32B at src+tid*32
// (fully coalesced). Write: thread tid emits 16B at dst+tid*16 (fully
// coalesced), sourcing chunk c = l15*16+kk*4+quad via LDS. XOR-swizzle
// (i ^ ((i>>4)&7)) keeps both LDS phases conflict-free.
// ---------------------------------------------------------------------------
__global__ __launch_bounds__(256)
void x_pack(const float* __restrict__ x, unsigned short* __restrict__ xp)
{
    __shared__ uintx4 lds[256];
    const int tid  = threadIdx.x;
    const int kk   = tid >> 6;
    const int quad = (tid >> 4) & 3;
    const int l15  = tid & 15;
    const int c    = l15 * 16 + kk * 4 + quad;       // source chunk for out pos tid
    const int wsw  = tid ^ ((tid >> 4) & 7);         // swizzled LDS write slot
    const int rsw  = c   ^ ((c   >> 4) & 7);         // swizzled LDS read slot

    for (int it = 0; it < 8; ++it) {
        const size_t slab = (size_t)it * 4096 + blockIdx.x;
        const float* src = x + slab * 2048;
        floatx4 f0 = *(const floatx4*)(src + tid * 8);
        floatx4 f1 = *(const floatx4*)(src + tid * 8 + 4);
        lds[wsw] = __builtin_bit_cast(uintx4, pack8(f0, f1));
        __syncthreads();
        uintx4 v = lds[rsw];
        *(uintx4*)(xp + slab * 2048 + tid * 8) = v;
        __syncthreads();
    }
}

// ---------------------------------------------------------------------------
// Phase 2: sequential scan with fused x-side GEMM. 16 blocks x 512 threads.
// Pipelined x-side: persistent xacc{R,Z,NI} hold step t's x-side sums,
// computed during step t-1's epilogue (independent of h -> scheduler
// interleaves the 12 x-MFMAs with the exp chains). Post-barrier critical
// path is only ds_read + 12 h-MFMAs + epilogue.
// Raw s_barrier + lgkmcnt-only fence keeps global traffic in flight.
// ---------------------------------------------------------------------------
__global__ __launch_bounds__(NTHREADS, 2)
void gru_scan(const unsigned short* __restrict__ xp,
              const float* __restrict__ h0,
              const float* __restrict__ masks,
              const float* __restrict__ w_ih,
              const float* __restrict__ w_hh,
              const float* __restrict__ b_ih,
              const float* __restrict__ b_hh,
              float* __restrict__ out)
{
    __shared__ unsigned short hbuf[2][EPB][136];   // rows = env, cols = j (+8 pad)

    const int tid  = threadIdx.x;
    const int wv   = tid >> 6;
    const int lane = tid & 63;
    const int quad = lane >> 4;
    const int l15  = lane & 15;
    const int envbase = blockIdx.x * EPB;
    const int j  = wv * 16 + l15;          // weight row for A-frag
    const int jb = wv * 16 + quad * 4;     // C-row base (4 consecutive j)

    const float gscale[3] = { -LOG2E, -LOG2E, 2.0f * LOG2E };

    // A-frags: w_ih and w_hh rows, pre-scaled
    bf16x8 bI[3][4], bH[3][4];
#pragma unroll
    for (int q = 0; q < 3; ++q) {
        const int col = q * HID + j;
        const float s = gscale[q];
#pragma unroll
        for (int kk = 0; kk < 4; ++kk) {
            const int kb = kk * 32 + quad * 8;
            floatx4 f0 = *(const floatx4*)(w_ih + col * HID + kb);
            floatx4 f1 = *(const floatx4*)(w_ih + col * HID + kb + 4);
            bI[q][kk] = pack8(f0 * s, f1 * s);
            floatx4 g0 = *(const floatx4*)(w_hh + col * HID + kb);
            floatx4 g1 = *(const floatx4*)(w_hh + col * HID + kb + 4);
            bH[q][kk] = pack8(g0 * s, g1 * s);
        }
    }
    // per-reg biases (C rows = j => bias varies across acc regs), pre-scaled
    floatx4 biasRv, biasZv, biasNIv, biasNHv;
    {
        floatx4 bi0 = *(const floatx4*)(b_ih + jb);
        floatx4 bh0 = *(const floatx4*)(b_hh + jb);
        floatx4 bi1 = *(const floatx4*)(b_ih + HID + jb);
        floatx4 bh1 = *(const floatx4*)(b_hh + HID + jb);
        floatx4 bi2 = *(const floatx4*)(b_ih + 2 * HID + jb);
        floatx4 bh2 = *(const floatx4*)(b_hh + 2 * HID + jb);
        biasRv  = (bi0 + bh0) * (-LOG2E);
        biasZv  = (bi1 + bh1) * (-LOG2E);
        biasNIv = bi2 * (2.0f * LOG2E);
        biasNHv = bh2 * (2.0f * LOG2E);
    }

    // init h (apply mask_0): lane owns env=l15, j=jb..jb+3
    float hC[4];
    {
        floatx4 h0v = *(const floatx4*)(h0 + (size_t)(envbase + l15) * HID + jb);
        float m0 = masks[envbase + l15];
#pragma unroll
        for (int i = 0; i < 4; ++i) hC[i] = h0v[i] * m0;
        uintx2 w; w[0] = cvt_pk_bf16(hC[0], hC[1]); w[1] = cvt_pk_bf16(hC[2], hC[3]);
        *(uintx2*)&hbuf[0][l15][jb] = w;
    }

    // packed-x base for this lane (same 4KB slab for all 8 waves of a block)
    const unsigned short* xbase = xp + (size_t)blockIdx.x * 2048
                                     + quad * 128 + l15 * 8;

    // x-frag double buffer: step(t) consumes buffer parity (t even -> xB holds
    // frag t+1); reloads the consumed buffer with frag t+3.
    bf16x8 xA[4], xB[4];
#pragma unroll
    for (int kk = 0; kk < 4; ++kk) {
        xA[kk] = __builtin_bit_cast(bf16x8, *(const ushortx8*)(xbase + kk * 512));
        xB[kk] = __builtin_bit_cast(bf16x8, *(const ushortx8*)(xbase + XP_T_STRIDE + kk * 512));
    }

    // persistent x-side accumulators for the CURRENT step (t=0 from frag0=xA)
    floatx4 xaccR = biasRv, xaccZ = biasZv, xaccNI = biasNIv;
#pragma unroll
    for (int kk = 0; kk < 4; ++kk) {
        xaccR  = __builtin_amdgcn_mfma_f32_16x16x32_bf16(bI[0][kk], xA[kk], xaccR,  0, 0, 0);
        xaccZ  = __builtin_amdgcn_mfma_f32_16x16x32_bf16(bI[1][kk], xA[kk], xaccZ,  0, 0, 0);
        xaccNI = __builtin_amdgcn_mfma_f32_16x16x32_bf16(bI[2][kk], xA[kk], xaccNI, 0, 0, 0);
    }
    // refill xA with frag(2) (consumed at step 1)
#pragma unroll
    for (int kk = 0; kk < 4; ++kk)
        xA[kk] = __builtin_bit_cast(bf16x8, *(const ushortx8*)(xbase + 2 * (size_t)XP_T_STRIDE + kk * 512));

    float mA = masks[(size_t)1 * NENV + envbase + l15];
    float mB = masks[(size_t)2 * NENV + envbase + l15];

    float* const outs = out;
    float* const hfin = out + (size_t)TSTEPS * NENV * HID;

    auto step = [&](int t, int p, bf16x8 (&xcN)[4], float& mreg) {
        // hbuf[p^1] writes must be visible to all waves; LDS-only drain,
        // global loads/stores stay outstanding across the barrier.
        asm volatile("s_waitcnt lgkmcnt(0)" ::: "memory");
        __builtin_amdgcn_s_barrier();
        __builtin_amdgcn_sched_barrier(0);

        // B-frags for h from LDS (lane col = env l15, k contiguous)
        bf16x8 ah[4];
#pragma unroll
        for (int kk = 0; kk < 4; ++kk) {
            ah[kk] = __builtin_bit_cast(bf16x8,
                *(const ushortx8*)&hbuf[p][l15][kk * 32 + quad * 8]);
        }

        // accumulators for step t: x-side sums were prepared last step
        floatx4 accR  = xaccR;
        floatx4 accZ  = xaccZ;
        floatx4 accNI = xaccNI;
        floatx4 accNH = biasNHv;

        // h-side MFMAs (the only MFMAs on the post-barrier critical path)
#pragma unroll
        for (int kk = 0; kk < 4; ++kk) {
            accR  = __builtin_amdgcn_mfma_f32_16x16x32_bf16(bH[0][kk], ah[kk], accR,  0, 0, 0);
            accZ  = __builtin_amdgcn_mfma_f32_16x16x32_bf16(bH[1][kk], ah[kk], accZ,  0, 0, 0);
            accNH = __builtin_amdgcn_mfma_f32_16x16x32_bf16(bH[2][kk], ah[kk], accNH, 0, 0, 0);
        }

        // prepare x-side sums for step t+1 (independent of h -> overlaps the
        // epilogue below in the scheduler)
        if (t + 1 < TSTEPS) {
            xaccR = biasRv; xaccZ = biasZv; xaccNI = biasNIv;
#pragma unroll
            for (int kk = 0; kk < 4; ++kk) {
                xaccR  = __builtin_amdgcn_mfma_f32_16x16x32_bf16(bI[0][kk], xcN[kk], xaccR,  0, 0, 0);
                xaccZ  = __builtin_amdgcn_mfma_f32_16x16x32_bf16(bI[1][kk], xcN[kk], xaccZ,  0, 0, 0);
                xaccNI = __builtin_amdgcn_mfma_f32_16x16x32_bf16(bI[2][kk], xcN[kk], xaccNI, 0, 0, 0);
            }
        }
        // refill the consumed frag buffer with frag(t+3)
        if (t + 3 < TSTEPS) {
            const unsigned short* xpp = xbase + (size_t)(t + 3) * XP_T_STRIDE;
#pragma unroll
            for (int kk = 0; kk < 4; ++kk)
                xcN[kk] = __builtin_bit_cast(bf16x8, *(const ushortx8*)(xpp + kk * 512));
        }
        // mask(t+1) for this step's epilogue; reload mreg with mask(t+3)
        float mn = mreg;
        mreg = (t + 3 < TSTEPS)
             ? masks[(size_t)(t + 3) * NENV + envbase + l15] : 1.0f;

        floatx4 hv;
#pragma unroll
        for (int i = 0; i < 4; ++i) {
            // accR/accZ = -log2e*pre  => sigmoid = rcp(1+2^acc)
            float r    = fast_rcp(1.0f + exp2_fast(accR[i]));
            float z    = fast_rcp(1.0f + exp2_fast(accZ[i]));
            // accNI/accNH = 2log2e*pre => tanh = 1 - 2*rcp(1+2^in)
            float ti   = accNI[i] + r * accNH[i];
            float n    = 1.0f - 2.0f * fast_rcp(1.0f + exp2_fast(ti));
            float hnew = n + z * (hC[i] - n);
            hv[i] = hnew;
            hC[i] = hnew * mn;
        }
        *(floatx4*)(outs + ((size_t)t * NENV + envbase + l15) * HID + jb) = hv;
        uintx2 w; w[0] = cvt_pk_bf16(hC[0], hC[1]); w[1] = cvt_pk_bf16(hC[2], hC[3]);
        *(uintx2*)&hbuf[p ^ 1][l15][jb] = w;
    };

    for (int t = 0; t < TSTEPS; t += 2) {
        step(t,     0, xB, mA);    // consumes frag t+1 from xB
        step(t + 1, 1, xA, mB);    // consumes frag t+2 from xA
    }
    // final state: mask(2048) forced to 1.0, so hC == h_{T-1}
    floatx4 hf; hf[0] = hC[0]; hf[1] = hC[1]; hf[2] = hC[2]; hf[3] = hC[3];
    *(floatx4*)(hfin + (size_t)(envbase + l15) * HID + jb) = hf;
}

// ---------------------------------------------------------------------------
// Fallback: round-1 fused kernel (used only if ws_size < XP_BYTES)
// ---------------------------------------------------------------------------
__global__ __launch_bounds__(NTHREADS, 2)
void gru_fused(const float* __restrict__ x,
               const float* __restrict__ h0,
               const float* __restrict__ masks,
               const float* __restrict__ w_ih,
               const float* __restrict__ w_hh,
               const float* __restrict__ b_ih,
               const float* __restrict__ b_hh,
               float* __restrict__ out)
{
    __shared__ unsigned short hbuf[2][EPB][136];

    const int tid  = threadIdx.x;
    const int wv   = tid >> 6;
    const int lane = tid & 63;
    const int quad = lane >> 4;
    const int l15  = lane & 15;
    const int envbase = blockIdx.x * EPB;
    const int j = wv * 16 + l15;

    bf16x8 bI[3][4], bH[3][4];
#pragma unroll
    for (int q = 0; q < 3; ++q) {
        const int col = q * HID + j;
#pragma unroll
        for (int kk = 0; kk < 4; ++kk) {
            const int kb = kk * 32 + quad * 8;
            floatx4 f0 = *(const floatx4*)(w_ih + col * HID + kb);
            floatx4 f1 = *(const floatx4*)(w_ih + col * HID + kb + 4);
            bI[q][kk] = pack8(f0, f1);
            floatx4 g0 = *(const floatx4*)(w_hh + col * HID + kb);
            floatx4 g1 = *(const floatx4*)(w_hh + col * HID + kb + 4);
            bH[q][kk] = pack8(g0, g1);
        }
    }

    const float biasR  = b_ih[j]           + b_hh[j];
    const float biasZ  = b_ih[HID + j]     + b_hh[HID + j];
    const float biasNI = b_ih[2 * HID + j];
    const float biasNH = b_hh[2 * HID + j];

    float hC[4];
    {
        floatx4 m0 = *(const floatx4*)(masks + envbase + quad * 4);
#pragma unroll
        for (int i = 0; i < 4; ++i) {
            const int e = quad * 4 + i;
            float h = h0[(envbase + e) * HID + j] * m0[i];
            hC[i] = h;
            hbuf[0][e][j] = f2bf(h);
        }
    }

    floatx4 xA[8], xB[8];
    {
        const float* xr = x + (size_t)(envbase + l15) * HID;
#pragma unroll
        for (int kk = 0; kk < 4; ++kk) {
            const int kb = kk * 32 + quad * 8;
            xA[2 * kk]     = *(const floatx4*)(xr + kb);
            xA[2 * kk + 1] = *(const floatx4*)(xr + kb + 4);
        }
    }

    float* const outs = out;
    float* const hfin = out + (size_t)TSTEPS * NENV * HID;

    auto step = [&](int t, int p, floatx4 (&xc)[8], floatx4 (&xn)[8]) {
        __syncthreads();
        bf16x8 ah[4];
#pragma unroll
        for (int kk = 0; kk < 4; ++kk) {
            ah[kk] = __builtin_bit_cast(bf16x8,
                *(const ushortx8*)&hbuf[p][l15][kk * 32 + quad * 8]);
        }
        bf16x8 ax[4];
#pragma unroll
        for (int kk = 0; kk < 4; ++kk) ax[kk] = pack8(xc[2 * kk], xc[2 * kk + 1]);

        if (t + 1 < TSTEPS) {
            const float* xr = x + (size_t)((t + 1) * NENV + envbase + l15) * HID;
#pragma unroll
            for (int kk = 0; kk < 4; ++kk) {
                const int kb = kk * 32 + quad * 8;
                xn[2 * kk]     = *(const floatx4*)(xr + kb);
                xn[2 * kk + 1] = *(const floatx4*)(xr + kb + 4);
            }
        }
        floatx4 mn;
        if (t + 1 < TSTEPS) {
            mn = *(const floatx4*)(masks + (size_t)(t + 1) * NENV + envbase + quad * 4);
        } else {
            mn[0] = mn[1] = mn[2] = mn[3] = 1.0f;
        }

        floatx4 accR  = {biasR,  biasR,  biasR,  biasR};
        floatx4 accZ  = {biasZ,  biasZ,  biasZ,  biasZ};
        floatx4 accNI = {biasNI, biasNI, biasNI, biasNI};
        floatx4 accNH = {biasNH, biasNH, biasNH, biasNH};
#pragma unroll
        for (int kk = 0; kk < 4; ++kk) {
            accR  = __builtin_amdgcn_mfma_f32_16x16x32_bf16(ax[kk], bI[0][kk], accR,  0, 0, 0);
            accR  = __builtin_amdgcn_mfma_f32_16x16x32_bf16(ah[kk], bH[0][kk], accR,  0, 0, 0);
            accZ  = __builtin_amdgcn_mfma_f32_16x16x32_bf16(ax[kk], bI[1][kk], accZ,  0, 0, 0);
            accZ  = __builtin_amdgcn_mfma_f32_16x16x32_bf16(ah[kk], bH[1][kk], accZ,  0, 0, 0);
            accNI = __builtin_amdgcn_mfma_f32_16x16x32_bf16(ax[kk], bI[2][kk], accNI, 0, 0, 0);
            accNH = __builtin_amdgcn_mfma_f32_16x16x32_bf16(ah[kk], bH[2][kk], accNH, 0, 0, 0);
        }

#pragma unroll
        for (int i = 0; i < 4; ++i) {
            const int e = quad * 4 + i;
            float r    = sigm(accR[i]);
            float z    = sigm(accZ[i]);
            float n    = tanh_fast(accNI[i] + r * accNH[i]);
            float hnew = n + z * (hC[i] - n);
            outs[((size_t)t * NENV + envbase + e) * HID + j] = hnew;
            if (t == TSTEPS - 1) hfin[(envbase + e) * HID + j] = hnew;
            float hm = hnew * mn[i];
            hC[i] = hm;
            hbuf[p ^ 1][e][j] = f2bf(hm);
        }
    };

    for (int t = 0; t < TSTEPS; t += 2) {
        step(t,     0, xA, xB);
        step(t + 1, 1, xB, xA);
    }
}

extern "C" void kernel_launch(void* const* d_in, const int* in_sizes, int n_in,
                              void* d_out, int out_size, void* d_ws, size_t ws_size,
                              hipStream_t stream) {
    const float* x    = (const float*)d_in[0];
    const float* h0   = (const float*)d_in[1];
    const float* mks  = (const float*)d_in[2];
    const float* w_ih = (const float*)d_in[3];
    const float* w_hh = (const float*)d_in[4];
    const float* b_ih = (const float*)d_in[5];
    const float* b_hh = (const float*)d_in[6];
    (void)in_sizes; (void)n_in; (void)out_size;

    if (ws_size >= XP_BYTES) {
        unsigned short* xp = (unsigned short*)d_ws;
        x_pack<<<dim3(4096), dim3(256), 0, stream>>>(x, xp);
        gru_scan<<<dim3(NBLK), dim3(NTHREADS), 0, stream>>>(xp, h0, mks, w_ih, w_hh,
                                                            b_ih, b_hh, (float*)d_out);
    } else {
        gru_fused<<<dim3(NBLK), dim3(NTHREADS), 0, stream>>>(
            x, h0, mks, w_ih, w_hh, b_ih, b_hh, (float*)d_out);
    }
}